// Round 3
// baseline (178.877 us; speedup 1.0000x reference)
//
#include <hip/hip_runtime.h>

// AdaptiveAngleConv round 3: implicit-GEMM bf16 MFMA, both operands from LDS.
// M=256 rotated channels, N = B*H*W. Block: M=256 x N=128 (2 rows x 64 w), 4 waves.
// Wave tile: M=128 x N=64 (mf=4, nf=2), 32x32x16 MFMA.
// K split: ci-half (2 x 32) outer, tap (9) inner. A-chunk [4 slot][256 m][8 ci] = 16 KB dbuf'd.

#define CIN 64
#define COUT 64
#define HH 128
#define WW 128
#define NB 16

typedef short bf16x8 __attribute__((ext_vector_type(8)));
typedef float f32x16 __attribute__((ext_vector_type(16)));

__device__ __constant__ int PERMS_d[4][9] = {
  {0,1,2,3,4,5,6,7,8},
  {3,0,1,6,4,2,7,8,5},
  {6,3,0,7,4,1,8,5,2},
  {7,6,3,8,4,0,5,2,1},
};

static __device__ __forceinline__ unsigned short f2bf(float f) {
  unsigned u = __builtin_bit_cast(unsigned, f);
  unsigned r = (u + 0x7FFFu + ((u >> 16) & 1u)) >> 16;
  return (unsigned short)r;
}

// A global layout matches the staging order exactly:
// e = ((((t*2 + h)*4 + s)*256 + m)*8 + j ; ci = h*32 + s*8 + j ; a = m>>6 ; co = m&63
__global__ void build_A_kernel(const float* __restrict__ wgt,
                               unsigned short* __restrict__ A) {
  const int e = blockIdx.x * 256 + threadIdx.x;   // 147456 total
  const int j = e & 7;
  const int m = (e >> 3) & 255;
  const int s = (e >> 11) & 3;
  const int h = (e >> 13) & 1;
  const int t = e >> 14;
  const int ci = h * 32 + s * 8 + j;
  const int a = m >> 6, co = m & 63;
  A[e] = f2bf(wgt[(co * CIN + ci) * 9 + PERMS_d[a][t]]);
}

// LDS map (bytes): xs [0, 16896): addr = r*4224 + s*1056 + wI*16 + j*2
//                  (r=0..3 rows h0-1..h0+2, s=ci-slot 0..3, wI=0..65, j=ci&7)
//                  As [16896 + buf*16384): addr = slot*4096 + m*16 + j*2
#define XS_ROW  4224
#define XS_SLOT 1056
#define AS_OFF  16896
#define AS_BUF  16384

__device__ __forceinline__ void stage_x(unsigned char* base, const float* __restrict__ x,
                                        int b, int h0, int w0, int tid, int h) {
  const int s = (tid >> 6) & 3;
  const int wi1 = tid & 63;
  const int ci0 = h * 32 + s * 8;
  // main columns wI = 1..64 (gw = w0..w0+63, always in-bounds)
  #pragma unroll
  for (int r = 0; r < 4; ++r) {
    const int gh = h0 - 1 + r;
    const unsigned dst = (unsigned)(r * XS_ROW + s * XS_SLOT + (1 + wi1) * 16);
    uint4 u4 = {0u, 0u, 0u, 0u};
    if (gh >= 0 && gh < HH) {
      const float* xp = x + ((size_t)(b * CIN + ci0) * HH + gh) * WW + (w0 + wi1);
      unsigned short v[8];
      #pragma unroll
      for (int q = 0; q < 8; ++q) v[q] = f2bf(xp[(size_t)q * HH * WW]);
      u4.x = (unsigned)v[0] | ((unsigned)v[1] << 16);
      u4.y = (unsigned)v[2] | ((unsigned)v[3] << 16);
      u4.z = (unsigned)v[4] | ((unsigned)v[5] << 16);
      u4.w = (unsigned)v[6] | ((unsigned)v[7] << 16);
    }
    *(uint4*)(base + dst) = u4;
  }
  // halo columns wI = 0 and 65
  if (tid < 32) {
    const int side = tid & 1;
    const int hs = (tid >> 1) & 3;
    const int hr = tid >> 3;
    const int wI = side ? 65 : 0;
    const int gw = w0 - 1 + wI;
    const int gh = h0 - 1 + hr;
    const int hci0 = h * 32 + hs * 8;
    const unsigned dst = (unsigned)(hr * XS_ROW + hs * XS_SLOT + wI * 16);
    uint4 u4 = {0u, 0u, 0u, 0u};
    if (gh >= 0 && gh < HH && gw >= 0 && gw < WW) {
      const float* xp = x + ((size_t)(b * CIN + hci0) * HH + gh) * WW + gw;
      unsigned short v[8];
      #pragma unroll
      for (int q = 0; q < 8; ++q) v[q] = f2bf(xp[(size_t)q * HH * WW]);
      u4.x = (unsigned)v[0] | ((unsigned)v[1] << 16);
      u4.y = (unsigned)v[2] | ((unsigned)v[3] << 16);
      u4.z = (unsigned)v[4] | ((unsigned)v[5] << 16);
      u4.w = (unsigned)v[6] | ((unsigned)v[7] << 16);
    }
    *(uint4*)(base + dst) = u4;
  }
}

__global__ __launch_bounds__(256, 2) void aconv_mfma2_kernel(
    const float* __restrict__ x,              // [B][CIN][H][W] fp32
    const unsigned short* __restrict__ Ag,    // [9][2][4][256][8] bf16
    const float* __restrict__ bias,           // [COUT]
    float* __restrict__ out)                  // [4][B][COUT][H][W] fp32
{
  __shared__ uint4 lds[3104];                 // 49,664 B
  unsigned char* base = (unsigned char*)lds;

  const int tid = threadIdx.x;
  const int lane = tid & 63;
  const int wid = tid >> 6;
  const int wm = wid >> 1;        // M-half: m0 = wm*128
  const int wn = wid & 1;         // output row within the 2-row tile
  const int half = lane >> 5;
  const int ln = lane & 31;

  int bid = blockIdx.x;
  const int wh = bid & 1;
  const int hp = (bid >> 1) & 63;
  const int b  = bid >> 7;
  const int w0 = wh * 64;
  const int h0 = hp * 2;

  const uint4* Ag4 = (const uint4*)Ag;

  // ---- prologue: A(chunk 0) loads, x(half 0) stage, A write, barrier ----
  uint4 ap[4];
  #pragma unroll
  for (int i = 0; i < 4; ++i) ap[i] = Ag4[tid + i * 256];
  stage_x(base, x, b, h0, w0, tid, 0);
  #pragma unroll
  for (int i = 0; i < 4; ++i)
    *(uint4*)(base + AS_OFF + (tid + i * 256) * 16) = ap[i];
  __syncthreads();

  f32x16 acc[4][2];
  #pragma unroll
  for (int mf = 0; mf < 4; ++mf)
    #pragma unroll
    for (int nf = 0; nf < 2; ++nf) acc[mf][nf] = (f32x16)(0.f);

  #pragma unroll
  for (int p = 0; p < 18; ++p) {
    const int cur = p & 1;
    const int h = p / 9, t = p % 9;
    const int dh = t / 3, dw = t % 3;

    // prefetch next A chunk
    uint4 an[4];
    if (p < 17) {
      const int pn = p + 1;
      const unsigned cb = (unsigned)((pn % 9) * 2048 + (pn / 9) * 1024);  // uint4 units
      #pragma unroll
      for (int i = 0; i < 4; ++i) an[i] = Ag4[cb + tid + i * 256];
    }

    // compute: 2 K-steps of 16
    #pragma unroll
    for (int kc = 0; kc < 2; ++kc) {
      const unsigned slotb = (unsigned)((kc * 2 + half));
      const unsigned char* Ab = base + AS_OFF + cur * AS_BUF + slotb * 4096
                                + (unsigned)(wm * 128 + ln) * 16;
      bf16x8 af[4];
      #pragma unroll
      for (int mf = 0; mf < 4; ++mf)
        af[mf] = *(const bf16x8*)(Ab + mf * 512);

      const unsigned char* Bb = base + (unsigned)(wn + dh) * XS_ROW + slotb * XS_SLOT
                                + (unsigned)(ln + dw) * 16;
      bf16x8 bfr[2];
      bfr[0] = *(const bf16x8*)(Bb);
      bfr[1] = *(const bf16x8*)(Bb + 32 * 16);

      #pragma unroll
      for (int mf = 0; mf < 4; ++mf)
        #pragma unroll
        for (int nf = 0; nf < 2; ++nf)
          acc[mf][nf] = __builtin_amdgcn_mfma_f32_32x32x16_bf16(af[mf], bfr[nf], acc[mf][nf], 0, 0, 0);
    }

    if (p == 8) __syncthreads();   // all waves done reading xs(h=0) before restage

    if (p < 17) {
      #pragma unroll
      for (int i = 0; i < 4; ++i)
        *(uint4*)(base + AS_OFF + (cur ^ 1) * AS_BUF + (tid + i * 256) * 16) = an[i];
      if (p == 8) stage_x(base, x, b, h0, w0, tid, 1);
      __syncthreads();
    }
  }

  // ---- epilogue: bias + store ----
  float bv[4][16];
  #pragma unroll
  for (int mf = 0; mf < 4; ++mf)
    #pragma unroll
    for (int g = 0; g < 16; ++g) {
      const int rowc = (g & 3) + 8 * (g >> 2) + 4 * half;
      bv[mf][g] = bias[(mf & 1) * 32 + rowc];
    }

  #pragma unroll
  for (int mf = 0; mf < 4; ++mf) {
    const int a = wm * 2 + (mf >> 1);
    #pragma unroll
    for (int nf = 0; nf < 2; ++nf) {
      const f32x16 v = acc[mf][nf];
      #pragma unroll
      for (int g = 0; g < 16; ++g) {
        const int rowc = (g & 3) + 8 * (g >> 2) + 4 * half;
        const int co = (mf & 1) * 32 + rowc;
        const size_t o = (((size_t)(a * NB + b) * COUT + co) * HH + (h0 + wn)) * WW
                         + (w0 + nf * 32 + ln);
        out[o] = v[g] + bv[mf][g];
      }
    }
  }
}

extern "C" void kernel_launch(void* const* d_in, const int* in_sizes, int n_in,
                              void* d_out, int out_size, void* d_ws, size_t ws_size,
                              hipStream_t stream) {
  const float* x    = (const float*)d_in[0];
  const float* wgt  = (const float*)d_in[1];
  const float* bias = (const float*)d_in[2];
  float* out = (float*)d_out;
  unsigned short* A = (unsigned short*)d_ws;   // 294,912 B

  build_A_kernel<<<576, 256, 0, stream>>>(wgt, A);
  aconv_mfma2_kernel<<<NB * (HH/2) * (WW/64), 256, 0, stream>>>(x, A, bias, out);
}